// Round 11
// baseline (128.672 us; speedup 1.0000x reference)
//
#include <hip/hip_runtime.h>
#include <hip/hip_bf16.h>

// GaussianCodebook: out[b,s,c] = mean_d((x[b,s,d]-cb[d,c])^2)
//                 = x2[m] + c2[n] - (2/D) * dot(x[m,:], cb[:,n])
// B=8 S=4096 D=512 C=2048  -> GEMM M=32768 N=2048 K=512 (bf16 MFMA) + epilogue.
// R11: two-output-tile blocks. R10 analysis: the epilogue store burst is
//     ~42us/CU of unoverlapped store time (every block bursts at the same
//     phase -> TLP can't hide it). Here each block computes two adjacent
//     128x128 n-tiles in a 32-step unified K-loop; steps 16-31 compute accB
//     AND store 4 elements/step of the finished accA -> output streams
//     under compute. Unlike R4: A panel is L2-hot (no refetch blow-up),
//     stores retire at L2 ack (~250cy) and gates only wait on stores >=2
//     steps old. Gates (in-order vmcnt): GATE(4) s<=16 & s=30, GATE(8)
//     s=17..29. x2/c2 preloaded to regs before the gated region.

typedef __attribute__((ext_vector_type(8))) short bf16x8;
typedef __attribute__((ext_vector_type(4))) float f32x4;

#define M_ROWS 32768
#define K_DIM  512
#define N_COLS 2048

__device__ __forceinline__ unsigned short f2bf(float f) {
    unsigned int u = __float_as_uint(f);
    return (unsigned short)((u + 0x7fffu + ((u >> 16) & 1u)) >> 16);  // RNE
}

__device__ __forceinline__ void gload_lds16(const void* g, void* l) {
    __builtin_amdgcn_global_load_lds(
        (const __attribute__((address_space(1))) unsigned int*)g,
        (__attribute__((address_space(3))) unsigned int*)l,
        16, 0, 0);
}

// ---- prep_x: cast x f32 -> bf16, and x2[m] = mean_d x^2 ----
__global__ __launch_bounds__(256) void prep_x_kernel(const float* __restrict__ x,
                                                     unsigned short* __restrict__ xb,
                                                     float* __restrict__ x2) {
    const int wid = threadIdx.x >> 6;
    const int lane = threadIdx.x & 63;
    const int row = (blockIdx.x << 2) + wid;
    const float4* p4 = reinterpret_cast<const float4*>(x + (size_t)row * K_DIM);
    float4 v0 = p4[lane];
    float4 v1 = p4[lane + 64];
    float ss = v0.x*v0.x + v0.y*v0.y + v0.z*v0.z + v0.w*v0.w
             + v1.x*v1.x + v1.y*v1.y + v1.z*v1.z + v1.w*v1.w;
    union { unsigned short us[4]; uint2 u2; } pa, pb;
    pa.us[0] = f2bf(v0.x); pa.us[1] = f2bf(v0.y); pa.us[2] = f2bf(v0.z); pa.us[3] = f2bf(v0.w);
    pb.us[0] = f2bf(v1.x); pb.us[1] = f2bf(v1.y); pb.us[2] = f2bf(v1.z); pb.us[3] = f2bf(v1.w);
    uint2* dst = reinterpret_cast<uint2*>(xb + (size_t)row * K_DIM);
    dst[lane]      = pa.u2;
    dst[lane + 64] = pb.u2;
    #pragma unroll
    for (int off = 32; off; off >>= 1) ss += __shfl_xor(ss, off);
    if (lane == 0) x2[row] = ss * (1.0f / (float)K_DIM);
}

// ---- prep_cb: transpose cb [K=512][N=2048] f32 -> cbT [N][K] bf16, scaled by 2/D = 2^-8 ----
__global__ __launch_bounds__(256) void prep_cb_kernel(const float* __restrict__ cb,
                                                      unsigned short* __restrict__ cbT) {
    __shared__ float tile[32][65];
    const int k0 = blockIdx.x * 32;
    const int n0 = blockIdx.y * 64;
    const int tx = threadIdx.x & 63;
    const int ty = threadIdx.x >> 6;
    #pragma unroll
    for (int i = 0; i < 8; ++i) {
        const int k = ty + i * 4;
        tile[k][tx] = cb[(size_t)(k0 + k) * N_COLS + n0 + tx];
    }
    __syncthreads();
    const int kc = threadIdx.x & 31;
    const int nr = threadIdx.x >> 5;
    #pragma unroll
    for (int i = 0; i < 8; ++i) {
        const int n = nr + i * 8;
        cbT[(size_t)(n0 + n) * K_DIM + k0 + kc] = f2bf(tile[kc][n] * 0.00390625f);
    }
}

// ---- c2[n] = mean_k cb[k][n]^2 ----
__global__ __launch_bounds__(256) void c2_kernel(const float* __restrict__ cb,
                                                 float* __restrict__ c2) {
    __shared__ float p[4][64];
    const int t = threadIdx.x;
    const int nl = t & 63;
    const int kc = t >> 6;
    const int n = blockIdx.x * 64 + nl;
    float s = 0.0f;
    for (int k = kc * 128; k < kc * 128 + 128; ++k) {
        float v = cb[(size_t)k * N_COLS + n];
        s += v * v;
    }
    p[kc][nl] = s;
    __syncthreads();
    if (t < 64) {
        c2[blockIdx.x * 64 + t] =
            (p[0][t] + p[1][t] + p[2][t] + p[3][t]) * (1.0f / (float)K_DIM);
    }
}

// ============ 2-tile 128x128 GEMM, 256 thr, stores in 2nd K-loop ============
// LDS per buf (shorts): A[128x32] @0 (4096), B[128x32] @4096 (4096) =16KB; x3=48KB.

__device__ __forceinline__ bf16x8 frag_ld(const unsigned short* h, int r, int lhi) {
    const int off = r * 32 + ((lhi ^ ((r >> 1) & 3)) << 3);
    return *reinterpret_cast<const bf16x8*>(&h[off]);
}

#define BAR()  do { asm volatile("" ::: "memory"); \
                    __builtin_amdgcn_s_barrier();  \
                    asm volatile("" ::: "memory"); } while (0)
#define GATE_(n) asm volatile("s_waitcnt vmcnt(" #n ")" ::: "memory")
#define GATE(n) GATE_(n)

__global__ __launch_bounds__(256, 2) void gemm_kernel(
        const unsigned short* __restrict__ A,   // [M][K] bf16 (xb)
        const unsigned short* __restrict__ Bt,  // [N][K] bf16 (scaled by 2^-8)
        const float* __restrict__ x2,
        const float* __restrict__ c2,
        float* __restrict__ out) {
    __shared__ unsigned short smem[3][8192];    // 48 KiB

    const int tid  = threadIdx.x;
    const int wid  = tid >> 6;
    const int lane = tid & 63;
    const int wr64 = (wid >> 1) * 64;       // 2 M-waves
    const int wc64 = (wid & 1) * 64;        // 2 N-waves
    const int l15 = lane & 15;
    const int lhi = lane >> 4;

    // 2048 blocks: 256 m-panels x 8 n-pairs. XCD swizzle: 256 consecutive
    // lbid per XCD; the 8 n-pairs of a panel are adjacent -> A panel L2-hot.
    const int bid  = blockIdx.x;
    const int lbid = (bid & 7) * 256 + (bid >> 3);
    const int m0  = (lbid >> 3) * 128;
    const int n0A = (lbid & 7) * 256;
    const int n0B = n0A + 128;

    const unsigned short* Ab  = A  + (size_t)m0 * K_DIM;
    const unsigned short* BbA = Bt + (size_t)n0A * K_DIM;
    const unsigned short* BbB = Bt + (size_t)n0B * K_DIM;

    // staging geometry: 512 16B-chunks/tile; thread covers chunks tid, 256+tid.
    const int c0   = tid;
    const int row0 = c0 >> 2;
    const size_t off0 = (size_t)row0 * K_DIM + ((size_t)(((c0 & 3) ^ ((row0 >> 1) & 3)) * 8));
    const int c1   = 256 + tid;
    const int row1 = c1 >> 2;
    const size_t off1 = (size_t)row1 * K_DIM + ((size_t)(((c1 & 3) ^ ((row1 >> 1) & 3)) * 8));

    f32x4 accA[4][4] = {};
    f32x4 accB[4][4] = {};

    // Preload epilogue constants BEFORE the gated region (no vmem inside).
    float x2v[16];
    #pragma unroll
    for (int mf = 0; mf < 4; ++mf)
        #pragma unroll
        for (int jj = 0; jj < 4; ++jj)
            x2v[mf * 4 + jj] = x2[m0 + wr64 + mf * 16 + lhi * 4 + jj];
    float c2oA[4];
    #pragma unroll
    for (int nf = 0; nf < 4; ++nf) c2oA[nf] = c2[n0A + wc64 + nf * 16 + l15];
    float* const outA = out + (size_t)(m0 + wr64 + lhi * 4) * N_COLS + n0A + wc64 + l15;

#define STAGE(KT) do {                                                         \
    const unsigned short* bb_ = ((KT) < 16) ? BbA : BbB;                       \
    const size_t ko_ = (size_t)(((KT) & 15) * 32);                             \
    gload_lds16(Ab  + off0 + ko_, &smem[(KT) % 3][wid * 512]);                 \
    gload_lds16(Ab  + off1 + ko_, &smem[(KT) % 3][2048 + wid * 512]);          \
    gload_lds16(bb_ + off0 + ko_, &smem[(KT) % 3][4096 + wid * 512]);          \
    gload_lds16(bb_ + off1 + ko_, &smem[(KT) % 3][6144 + wid * 512]); } while (0)

#define STORE1(IDX) do {                                                       \
    const int i_ = (IDX);                                                      \
    const int mf_ = i_ >> 4, nf_ = (i_ >> 2) & 3, jj_ = i_ & 3;                \
    outA[(size_t)(mf_ * 16 + jj_) * N_COLS + nf_ * 16] =                       \
        x2v[mf_ * 4 + jj_] + c2oA[nf_] - accA[mf_][nf_][jj_]; } while (0)

// STEP(S, ACC, GN, DOG, DOST): stage S+2 (if <=31), MFMA buf S%3 into ACC,
// gate GN (if DOG), 4 accA stores (if DOST), barrier.
#define STEP(S, ACC, GN, DOG, DOST)                                            \
  {                                                                            \
    if ((S) <= 29) STAGE((S) + 2);                                             \
    const unsigned short* cbuf = smem[(S) % 3];                                \
    bf16x8 b[4];                                                               \
    _Pragma("unroll")                                                          \
    for (int nf = 0; nf < 4; ++nf)                                             \
        b[nf] = frag_ld(cbuf + 4096, wc64 + nf * 16 + l15, lhi);               \
    __builtin_amdgcn_s_setprio(1);                                             \
    _Pragma("unroll")                                                          \
    for (int mf = 0; mf < 4; ++mf) {                                           \
        const bf16x8 a = frag_ld(cbuf, wr64 + mf * 16 + l15, lhi);             \
        _Pragma("unroll")                                                      \
        for (int nf = 0; nf < 4; ++nf)                                         \
            ACC[mf][nf] = __builtin_amdgcn_mfma_f32_16x16x32_bf16(a, b[nf], ACC[mf][nf], 0, 0, 0); \
    }                                                                          \
    __builtin_amdgcn_s_setprio(0);                                             \
    if (DOG) { GATE(GN); }                                                     \
    if (DOST) { STORE1(((S) - 16) * 4 + 0); STORE1(((S) - 16) * 4 + 1);        \
                STORE1(((S) - 16) * 4 + 2); STORE1(((S) - 16) * 4 + 3); }      \
    BAR();                                                                     \
  }

    // prologue
    STAGE(0);
    STAGE(1);
    GATE(4);
    BAR();

    // tile A: steps 0..15 (no stores). Gates: ensure tile s+1 landed; only
    // tile s+2's 4 loads are newer -> GATE(4).
    STEP(0,  accA, 4, 1, 0) STEP(1,  accA, 4, 1, 0) STEP(2,  accA, 4, 1, 0)
    STEP(3,  accA, 4, 1, 0) STEP(4,  accA, 4, 1, 0) STEP(5,  accA, 4, 1, 0)
    STEP(6,  accA, 4, 1, 0) STEP(7,  accA, 4, 1, 0) STEP(8,  accA, 4, 1, 0)
    STEP(9,  accA, 4, 1, 0) STEP(10, accA, 4, 1, 0) STEP(11, accA, 4, 1, 0)
    STEP(12, accA, 4, 1, 0) STEP(13, accA, 4, 1, 0) STEP(14, accA, 4, 1, 0)
    STEP(15, accA, 4, 1, 0)
    // tile B: steps 16..31, 4 accA stores/step. s=16: newer-than-loads_17 =
    // loads_18 only -> GATE(4). s=17..29: stores_{s-1}(4)+loads_{s+2}(4) ->
    // GATE(8). s=30: loads_31 watched; newer = stores_29(4) -> GATE(4).
    // s=31: no gate (last buf gated at s=30).
    STEP(16, accB, 4, 1, 1) STEP(17, accB, 8, 1, 1) STEP(18, accB, 8, 1, 1)
    STEP(19, accB, 8, 1, 1) STEP(20, accB, 8, 1, 1) STEP(21, accB, 8, 1, 1)
    STEP(22, accB, 8, 1, 1) STEP(23, accB, 8, 1, 1) STEP(24, accB, 8, 1, 1)
    STEP(25, accB, 8, 1, 1) STEP(26, accB, 8, 1, 1) STEP(27, accB, 8, 1, 1)
    STEP(28, accB, 8, 1, 1) STEP(29, accB, 8, 1, 1) STEP(30, accB, 4, 1, 1)
    STEP(31, accB, 0, 0, 1)

#undef STAGE
#undef STORE1
#undef STEP

    // epilogue: store tile B (64 KB/block burst -- half of R10's)
    float c2oB[4];
    #pragma unroll
    for (int nf = 0; nf < 4; ++nf) c2oB[nf] = c2[n0B + wc64 + nf * 16 + l15];
    float* const outB = out + (size_t)(m0 + wr64 + lhi * 4) * N_COLS + n0B + wc64 + l15;
    #pragma unroll
    for (int mf = 0; mf < 4; ++mf)
        #pragma unroll
        for (int nf = 0; nf < 4; ++nf)
            #pragma unroll
            for (int jj = 0; jj < 4; ++jj)
                outB[(size_t)(mf * 16 + jj) * N_COLS + nf * 16] =
                    x2v[mf * 4 + jj] + c2oB[nf] - accB[mf][nf][jj];
}

extern "C" void kernel_launch(void* const* d_in, const int* in_sizes, int n_in,
                              void* d_out, int out_size, void* d_ws, size_t ws_size,
                              hipStream_t stream) {
    const float* x  = (const float*)d_in[0];   // [8,4096,512]
    const float* cb = (const float*)d_in[1];   // [1,1,512,2048]
    float* out = (float*)d_out;                // [8,4096,2048]

    char* ws = (char*)d_ws;
    unsigned short* xb  = (unsigned short*)ws;                               // 32 MB
    unsigned short* cbT = (unsigned short*)(ws + (size_t)33554432);          // 2 MB
    float* x2 = (float*)(ws + (size_t)33554432 + 2097152);                   // 128 KB
    float* c2 = (float*)(ws + (size_t)33554432 + 2097152 + 131072);          // 8 KB

    prep_x_kernel<<<M_ROWS / 4, 256, 0, stream>>>(x, xb, x2);
    prep_cb_kernel<<<dim3(16, 32), 256, 0, stream>>>(cb, cbT);
    c2_kernel<<<N_COLS / 64, 256, 0, stream>>>(cb, c2);
    gemm_kernel<<<dim3((M_ROWS / 128) * (N_COLS / 256)), 256, 0, stream>>>(xb, cbT, x2, c2, out);
}

// Round 12
// 127.880 us; speedup vs baseline: 1.0062x; 1.0062x over previous
//
#include <hip/hip_runtime.h>
#include <hip/hip_bf16.h>

// GaussianCodebook: out[b,s,c] = mean_d((x[b,s,d]-cb[d,c])^2)
//                 = x2[m] + c2[n] - (2/D) * dot(x[m,:], cb[:,n])
// B=8 S=4096 D=512 C=2048  -> GEMM M=32768 N=2048 K=512 (bf16 MFMA) + epilogue.
// R12: R10 + REGISTER-DOUBLE-BUFFERED FRAGMENTS (the m196/m201 interleave).
//     Diagnosis: R8's counters (MfmaUtil 14 + VALU 15 + mem 29% = parts sum
//     serially) show the ds_read->MFMA latency chain in each step serialized
//     the pipes. Fix: step T prefetches tile T+1's 8 fragments into register
//     set (T+1)&1 BEFORE the MFMA cluster consuming set T&1 -> MFMA never
//     waits on LDS. 4-buf LDS ring (64KB), stage 3 ahead; gate algebra:
//     end-of-S GATE(4) leaves only stage S+3 in flight => tiles <= S+2
//     landed => reads at T (tile T+1) covered by end-of-(T-1) gate. Loads
//     fly ~3 steps (~1200cy) so even HBM misses don't stall.

typedef __attribute__((ext_vector_type(8))) short bf16x8;
typedef __attribute__((ext_vector_type(4))) float f32x4;

#define M_ROWS 32768
#define K_DIM  512
#define N_COLS 2048

__device__ __forceinline__ unsigned short f2bf(float f) {
    unsigned int u = __float_as_uint(f);
    return (unsigned short)((u + 0x7fffu + ((u >> 16) & 1u)) >> 16);  // RNE
}

__device__ __forceinline__ void gload_lds16(const void* g, void* l) {
    __builtin_amdgcn_global_load_lds(
        (const __attribute__((address_space(1))) unsigned int*)g,
        (__attribute__((address_space(3))) unsigned int*)l,
        16, 0, 0);
}

// ---- prep_x: cast x f32 -> bf16, and x2[m] = mean_d x^2 ----
__global__ __launch_bounds__(256) void prep_x_kernel(const float* __restrict__ x,
                                                     unsigned short* __restrict__ xb,
                                                     float* __restrict__ x2) {
    const int wid = threadIdx.x >> 6;
    const int lane = threadIdx.x & 63;
    const int row = (blockIdx.x << 2) + wid;
    const float4* p4 = reinterpret_cast<const float4*>(x + (size_t)row * K_DIM);
    float4 v0 = p4[lane];
    float4 v1 = p4[lane + 64];
    float ss = v0.x*v0.x + v0.y*v0.y + v0.z*v0.z + v0.w*v0.w
             + v1.x*v1.x + v1.y*v1.y + v1.z*v1.z + v1.w*v1.w;
    union { unsigned short us[4]; uint2 u2; } pa, pb;
    pa.us[0] = f2bf(v0.x); pa.us[1] = f2bf(v0.y); pa.us[2] = f2bf(v0.z); pa.us[3] = f2bf(v0.w);
    pb.us[0] = f2bf(v1.x); pb.us[1] = f2bf(v1.y); pb.us[2] = f2bf(v1.z); pb.us[3] = f2bf(v1.w);
    uint2* dst = reinterpret_cast<uint2*>(xb + (size_t)row * K_DIM);
    dst[lane]      = pa.u2;
    dst[lane + 64] = pb.u2;
    #pragma unroll
    for (int off = 32; off; off >>= 1) ss += __shfl_xor(ss, off);
    if (lane == 0) x2[row] = ss * (1.0f / (float)K_DIM);
}

// ---- prep_cb: transpose cb [K=512][N=2048] f32 -> cbT [N][K] bf16, scaled by 2/D = 2^-8 ----
__global__ __launch_bounds__(256) void prep_cb_kernel(const float* __restrict__ cb,
                                                      unsigned short* __restrict__ cbT) {
    __shared__ float tile[32][65];
    const int k0 = blockIdx.x * 32;
    const int n0 = blockIdx.y * 64;
    const int tx = threadIdx.x & 63;
    const int ty = threadIdx.x >> 6;
    #pragma unroll
    for (int i = 0; i < 8; ++i) {
        const int k = ty + i * 4;
        tile[k][tx] = cb[(size_t)(k0 + k) * N_COLS + n0 + tx];
    }
    __syncthreads();
    const int kc = threadIdx.x & 31;
    const int nr = threadIdx.x >> 5;
    #pragma unroll
    for (int i = 0; i < 8; ++i) {
        const int n = nr + i * 8;
        cbT[(size_t)(n0 + n) * K_DIM + k0 + kc] = f2bf(tile[kc][n] * 0.00390625f);
    }
}

// ---- c2[n] = mean_k cb[k][n]^2 ----
__global__ __launch_bounds__(256) void c2_kernel(const float* __restrict__ cb,
                                                 float* __restrict__ c2) {
    __shared__ float p[4][64];
    const int t = threadIdx.x;
    const int nl = t & 63;
    const int kc = t >> 6;
    const int n = blockIdx.x * 64 + nl;
    float s = 0.0f;
    for (int k = kc * 128; k < kc * 128 + 128; ++k) {
        float v = cb[(size_t)k * N_COLS + n];
        s += v * v;
    }
    p[kc][nl] = s;
    __syncthreads();
    if (t < 64) {
        c2[blockIdx.x * 64 + t] =
            (p[0][t] + p[1][t] + p[2][t] + p[3][t]) * (1.0f / (float)K_DIM);
    }
}

// ============ 128x128 GEMM, 256 thr, 4-ring + reg-dbuf frags ============
// LDS per buf (shorts): A[128x32] @0 (4096), B[128x32] @4096 (4096) =16KB; x4=64KB.

__device__ __forceinline__ bf16x8 frag_ld(const unsigned short* h, int r, int lhi) {
    const int off = r * 32 + ((lhi ^ ((r >> 1) & 3)) << 3);
    return *reinterpret_cast<const bf16x8*>(&h[off]);
}

#define BAR()  do { asm volatile("" ::: "memory"); \
                    __builtin_amdgcn_s_barrier();  \
                    asm volatile("" ::: "memory"); } while (0)
#define GATE_(n) asm volatile("s_waitcnt vmcnt(" #n ")" ::: "memory")
#define GATE(n) GATE_(n)

__global__ __launch_bounds__(256, 2) void gemm_kernel(
        const unsigned short* __restrict__ A,   // [M][K] bf16 (xb)
        const unsigned short* __restrict__ Bt,  // [N][K] bf16 (scaled by 2^-8)
        const float* __restrict__ x2,
        const float* __restrict__ c2,
        float* __restrict__ out) {
    __shared__ unsigned short smem[4][8192];    // 64 KiB

    const int tid  = threadIdx.x;
    const int wid  = tid >> 6;
    const int lane = tid & 63;
    const int wr64 = (wid >> 1) * 64;       // 2 M-waves
    const int wc64 = (wid & 1) * 64;        // 2 N-waves
    const int l15 = lane & 15;
    const int lhi = lane >> 4;

    // T1: XCD-bijective swizzle (4096 blocks -> 512/XCD); panel-major: the 16
    // n-blocks of one m-panel run consecutively -> A panel + cbT L2-resident.
    const int bid  = blockIdx.x;
    const int lbid = (bid & 7) * 512 + (bid >> 3);
    const int m0 = (lbid >> 4) * 128;
    const int n0 = (lbid & 15) * 128;

    const unsigned short* Ab = A  + (size_t)m0 * K_DIM;
    const unsigned short* Bb = Bt + (size_t)n0 * K_DIM;

    // staging geometry: 512 16B-chunks/tile; thread covers chunks tid, 256+tid.
    const int c0   = tid;
    const int row0 = c0 >> 2;
    const size_t off0 = (size_t)row0 * K_DIM + ((size_t)(((c0 & 3) ^ ((row0 >> 1) & 3)) * 8));
    const int c1   = 256 + tid;
    const int row1 = c1 >> 2;
    const size_t off1 = (size_t)row1 * K_DIM + ((size_t)(((c1 & 3) ^ ((row1 >> 1) & 3)) * 8));

    f32x4 acc[4][4] = {};
    bf16x8 aR0[4], bR0[4], aR1[4], bR1[4];   // two named fragment sets

#define STAGE(KT) do {                                                         \
    gload_lds16(Ab + off0 + (KT) * 32, &smem[(KT) & 3][wid * 512]);            \
    gload_lds16(Ab + off1 + (KT) * 32, &smem[(KT) & 3][2048 + wid * 512]);     \
    gload_lds16(Bb + off0 + (KT) * 32, &smem[(KT) & 3][4096 + wid * 512]);     \
    gload_lds16(Bb + off1 + (KT) * 32, &smem[(KT) & 3][6144 + wid * 512]); } while (0)

#define READF(KT, AR, BR) do {                                                 \
    const unsigned short* fb_ = smem[(KT) & 3];                                \
    _Pragma("unroll")                                                          \
    for (int q = 0; q < 4; ++q) {                                              \
        AR[q] = frag_ld(fb_,        wr64 + q * 16 + l15, lhi);                 \
        BR[q] = frag_ld(fb_ + 4096, wc64 + q * 16 + l15, lhi);                 \
    } } while (0)

#define MFMA16(AR, BR) do {                                                    \
    __builtin_amdgcn_s_setprio(1);                                             \
    _Pragma("unroll")                                                          \
    for (int mf = 0; mf < 4; ++mf)                                             \
        _Pragma("unroll")                                                      \
        for (int nf = 0; nf < 4; ++nf)                                         \
            acc[mf][nf] = __builtin_amdgcn_mfma_f32_16x16x32_bf16(AR[mf], BR[nf], acc[mf][nf], 0, 0, 0); \
    __builtin_amdgcn_s_setprio(0); } while (0)

// STEP(T): stage T+3; prefetch frags(T+1) into set (T+1)&1; MFMA set T&1;
// gate: T<=12 GATE(4) (=> tiles <= T+2 landed, covers next step's reads);
// T==13 GATE(0) (drain: step 14 reads tile 15); T>=14 none.
#define STEP(T, ARc, BRc, ARn, BRn)                                            \
  {                                                                            \
    if ((T) + 3 <= 15) STAGE((T) + 3);                                         \
    if ((T) < 15) READF((T) + 1, ARn, BRn);                                    \
    MFMA16(ARc, BRc);                                                          \
    if ((T) <= 12) { GATE(4); } else if ((T) == 13) { GATE(0); }               \
    BAR();                                                                     \
  }

    // prologue: stages 0,1,2 in flight (12 loads); GATE(4) -> tiles 0,1
    // landed (stage 2 remains); BAR; prefetch frags(0) into set 0.
    STAGE(0);
    STAGE(1);
    STAGE(2);
    GATE(4);
    BAR();
    READF(0, aR0, bR0);

    STEP(0,  aR0, bR0, aR1, bR1)  STEP(1,  aR1, bR1, aR0, bR0)
    STEP(2,  aR0, bR0, aR1, bR1)  STEP(3,  aR1, bR1, aR0, bR0)
    STEP(4,  aR0, bR0, aR1, bR1)  STEP(5,  aR1, bR1, aR0, bR0)
    STEP(6,  aR0, bR0, aR1, bR1)  STEP(7,  aR1, bR1, aR0, bR0)
    STEP(8,  aR0, bR0, aR1, bR1)  STEP(9,  aR1, bR1, aR0, bR0)
    STEP(10, aR0, bR0, aR1, bR1)  STEP(11, aR1, bR1, aR0, bR0)
    STEP(12, aR0, bR0, aR1, bR1)  STEP(13, aR1, bR1, aR0, bR0)
    STEP(14, aR0, bR0, aR1, bR1)  STEP(15, aR1, bR1, aR0, bR0)

#undef STAGE
#undef READF
#undef MFMA16
#undef STEP

    // epilogue: C/D layout col = lane&15, row = (lane>>4)*4 + reg
    #pragma unroll
    for (int mf = 0; mf < 4; ++mf) {
        const int mrow = m0 + wr64 + mf * 16 + lhi * 4;
        const float xv0 = x2[mrow + 0];
        const float xv1 = x2[mrow + 1];
        const float xv2 = x2[mrow + 2];
        const float xv3 = x2[mrow + 3];
        #pragma unroll
        for (int nf = 0; nf < 4; ++nf) {
            const int col = n0 + wc64 + nf * 16 + l15;
            const float cv = c2[col];
            float* o = out + (size_t)mrow * N_COLS + col;
            o[0 * N_COLS] = xv0 + cv - acc[mf][nf][0];
            o[1 * N_COLS] = xv1 + cv - acc[mf][nf][1];
            o[2 * N_COLS] = xv2 + cv - acc[mf][nf][2];
            o[3 * N_COLS] = xv3 + cv - acc[mf][nf][3];
        }
    }
}

extern "C" void kernel_launch(void* const* d_in, const int* in_sizes, int n_in,
                              void* d_out, int out_size, void* d_ws, size_t ws_size,
                              hipStream_t stream) {
    const float* x  = (const float*)d_in[0];   // [8,4096,512]
    const float* cb = (const float*)d_in[1];   // [1,1,512,2048]
    float* out = (float*)d_out;                // [8,4096,2048]

    char* ws = (char*)d_ws;
    unsigned short* xb  = (unsigned short*)ws;                               // 32 MB
    unsigned short* cbT = (unsigned short*)(ws + (size_t)33554432);          // 2 MB
    float* x2 = (float*)(ws + (size_t)33554432 + 2097152);                   // 128 KB
    float* c2 = (float*)(ws + (size_t)33554432 + 2097152 + 131072);          // 8 KB

    prep_x_kernel<<<M_ROWS / 4, 256, 0, stream>>>(x, xb, x2);
    prep_cb_kernel<<<dim3(16, 32), 256, 0, stream>>>(cb, cbT);
    c2_kernel<<<N_COLS / 64, 256, 0, stream>>>(cb, c2);
    gemm_kernel<<<dim3((M_ROWS / 128) * (N_COLS / 128)), 256, 0, stream>>>(xb, cbT, x2, c2, out);
}